// Round 3
// baseline (55.479 us; speedup 1.0000x reference)
//
#include <hip/hip_runtime.h>
#include <math.h>

#define BATCH 65536
#define XPER  576      // 24*24 floats per element
#define NBLK  2048
#define EPB   32       // elements per block
#define ITERS (EPB / 16)

// ws float layout: [0..3] sum_z, [4..7] sum_z2   (zeroed by memset node)

// ---------------------------------------------------------------- K1
// Pool (direct from global, no staging) + folded 2-layer unitary + probs
// + WHT z-outputs + BN partial sums.
__global__ __launch_bounds__(256) void circuit_kernel(
        const float* __restrict__ x, const float* __restrict__ params,
        float* __restrict__ out, float* __restrict__ accums) {
    __shared__ float sU[512];          // Ur row-major, then Ui
    __shared__ float sg[48];           // 8 gates x {c,s,epr,epi,emr,emi}
    __shared__ float spart[8];

    const int t = threadIdx.x;
    const int e = t >> 4;      // element within group of 16
    const int p = t & 15;      // pool index == state row owned by this lane

    if (t < 8) {
        spart[t] = 0.0f;
        // gate t = (layer l = t>>2, wire w = t&3)
        float phi   = params[t * 3 + 0];
        float theta = params[t * 3 + 1];
        float omega = params[t * 3 + 2];
        float apo = 0.5f * (phi + omega), amo = 0.5f * (phi - omega);
        sg[t * 6 + 0] = cosf(0.5f * theta);
        sg[t * 6 + 1] = sinf(0.5f * theta);
        sg[t * 6 + 2] = cosf(apo);           // epr   (ep = e^{-i(phi+omega)/2})
        sg[t * 6 + 3] = -sinf(apo);          // epi
        sg[t * 6 + 4] = cosf(amo);           // emr   (em = e^{+i(phi-omega)/2})
        sg[t * 6 + 5] = sinf(amo);           // emi
    }
    __syncthreads();

    if (t < 16) {
        const int j = t;       // this lane owns column j of M (state' = M state)
        float Mr[16], Mi[16];
#pragma unroll
        for (int i = 0; i < 16; ++i) { Mr[i] = (i == j) ? 1.0f : 0.0f; Mi[i] = 0.0f; }

#pragma unroll
        for (int l = 0; l < 2; ++l) {
#pragma unroll
            for (int w = 0; w < 4; ++w) {
                const int g = l * 4 + w;
                float c   = sg[g * 6 + 0], s   = sg[g * 6 + 1];
                float epr = sg[g * 6 + 2], epi = sg[g * 6 + 3];
                float emr = sg[g * 6 + 4], emi = sg[g * 6 + 5];
                float m00r =  epr * c, m00i =  epi * c;    // ep*c
                float m01r = -emr * s, m01i = -emi * s;    // -em*s
                float m10r =  emr * s, m10i = -emi * s;    // conj(em)*s
                float m11r =  epr * c, m11i = -epi * c;    // conj(ep)*c
                const int mask = 1 << (3 - w);
#pragma unroll
                for (int i = 0; i < 16; ++i) {
                    if (i & mask) continue;
                    int i1 = i | mask;
                    float r0 = Mr[i],  q0 = Mi[i];
                    float r1 = Mr[i1], q1 = Mi[i1];
                    Mr[i]  = m00r * r0 - m00i * q0 + m01r * r1 - m01i * q1;
                    Mi[i]  = m00r * q0 + m00i * r0 + m01r * q1 + m01i * r1;
                    Mr[i1] = m10r * r0 - m10i * q0 + m11r * r1 - m11i * q1;
                    Mi[i1] = m10r * q0 + m10i * r0 + m11r * q1 + m11i * r1;
                }
            }
            // CNOT ring: r = l%3+1; XOR permutations applied sequentially
            const int r = (l % 3) + 1;
#pragma unroll
            for (int w = 0; w < 4; ++w) {
                int tq = (w + r) & 3;
                int cb = 3 - w, tb = 3 - tq;
#pragma unroll
                for (int i = 0; i < 16; ++i) {
                    int pi = i ^ (((i >> cb) & 1) << tb);
                    if (pi > i) {
                        float tr = Mr[i]; Mr[i] = Mr[pi]; Mr[pi] = tr;
                        float ti = Mi[i]; Mi[i] = Mi[pi]; Mi[pi] = ti;
                    }
                }
            }
        }
#pragma unroll
        for (int i = 0; i < 16; ++i) {
            sU[i * 16 + j]       = Mr[i];
            sU[256 + i * 16 + j] = Mi[i];
        }
    }
    __syncthreads();

    // U row p -> registers (float4 LDS reads, once per kernel)
    float ur[16], ui[16];
    {
        const float4* u4 = (const float4*)(sU + p * 16);
        const float4* v4 = (const float4*)(sU + 256 + p * 16);
#pragma unroll
        for (int q = 0; q < 4; ++q) {
            float4 a = u4[q], b = v4[q];
            ur[4 * q + 0] = a.x; ur[4 * q + 1] = a.y; ur[4 * q + 2] = a.z; ur[4 * q + 3] = a.w;
            ui[4 * q + 0] = b.x; ui[4 * q + 1] = b.y; ui[4 * q + 2] = b.z; ui[4 * q + 3] = b.w;
        }
    }

    // writer lane -> output channel (z_w lives at group-lane 1<<(3-w))
    int c = -1;
    if      (p == 8) c = 0;
    else if (p == 4) c = 1;
    else if (p == 2) c = 2;
    else if (p == 1) c = 3;

    float accz = 0.0f, accz2 = 0.0f;
    const int base = blockIdx.x * EPB;

    for (int it = 0; it < ITERS; ++it) {
        const int img = base + it * 16 + e;
        // 6x6 average pool straight from global: 18 aligned float2 loads
        const float* ip = x + (size_t)img * XPER + ((p >> 2) * 6) * 24 + (p & 3) * 6;
        float sum = 0.0f;
#pragma unroll
        for (int i = 0; i < 6; ++i) {
            const float2* rp = (const float2*)(ip + i * 24);
            float2 a2 = rp[0], b2 = rp[1], d2 = rp[2];
            sum += a2.x + a2.y + b2.x + b2.y + d2.x + d2.y;
        }
        float v = sum * (1.0f / 36.0f);

        // norm^2 over the 16-lane group
        float n2 = v * v;
        n2 += __shfl_xor(n2, 1);
        n2 += __shfl_xor(n2, 2);
        n2 += __shfl_xor(n2, 4);
        n2 += __shfl_xor(n2, 8);

        // state_p = sum_j U[p][j] * v_j   (input state is real)
        float sr = 0.0f, si = 0.0f;
#pragma unroll
        for (int j = 0; j < 16; ++j) {
            float vj = __shfl(v, j, 16);
            sr = fmaf(ur[j], vj, sr);
            si = fmaf(ui[j], vj, si);
        }
        float prob = (sr * sr + si * si) / n2;

        // 16-pt Walsh-Hadamard: lane m holds sum_p (-1)^{popc(m&p)} prob_p
        float a = prob, o;
        o = __shfl_xor(a, 1); a = (t & 1) ? (o - a) : (a + o);
        o = __shfl_xor(a, 2); a = (t & 2) ? (o - a) : (a + o);
        o = __shfl_xor(a, 4); a = (t & 4) ? (o - a) : (a + o);
        o = __shfl_xor(a, 8); a = (t & 8) ? (o - a) : (a + o);

        if (c >= 0) {
            out[(size_t)img * 4 + c] = a;   // raw z, normalized by K2
            accz  += a;
            accz2 += a * a;
        }
    }

    if (c >= 0) {
        atomicAdd(&spart[c], accz);
        atomicAdd(&spart[4 + c], accz2);
    }
    __syncthreads();
    if (t < 8) atomicAdd(&accums[t], spart[t]);
}

// ---------------------------------------------------------------- K2
// Finalize BN stats (per-block, cheap) + apply affine to out in place.
__global__ __launch_bounds__(256) void bn_apply(float* __restrict__ out,
                                                const float* __restrict__ accums,
                                                const float* __restrict__ gamma,
                                                const float* __restrict__ beta) {
    __shared__ float sc[8];
    const int t = threadIdx.x;
    if (t < 4) {
        float mu  = accums[t] * (1.0f / BATCH);
        float var = accums[4 + t] * (1.0f / BATCH) - mu * mu;
        float a = gamma[t] * rsqrtf(var + 1e-5f);
        sc[t]     = a;
        sc[4 + t] = beta[t] - mu * a;
    }
    __syncthreads();
    int i = blockIdx.x * 256 + t;   // one float4 (one element) each
    float4 z = ((float4*)out)[i];
    z.x = fmaf(z.x, sc[0], sc[4]);
    z.y = fmaf(z.y, sc[1], sc[5]);
    z.z = fmaf(z.z, sc[2], sc[6]);
    z.w = fmaf(z.w, sc[3], sc[7]);
    ((float4*)out)[i] = z;
}

extern "C" void kernel_launch(void* const* d_in, const int* in_sizes, int n_in,
                              void* d_out, int out_size, void* d_ws, size_t ws_size,
                              hipStream_t stream) {
    const float* x      = (const float*)d_in[0];
    const float* params = (const float*)d_in[1];
    const float* gamma  = (const float*)d_in[2];
    const float* beta   = (const float*)d_in[3];
    float* out = (float*)d_out;
    float* ws  = (float*)d_ws;

    hipMemsetAsync(ws, 0, 8 * sizeof(float), stream);   // zero BN accumulators
    hipLaunchKernelGGL(circuit_kernel, dim3(NBLK), dim3(256), 0, stream,
                       x, params, out, ws);
    hipLaunchKernelGGL(bn_apply, dim3(BATCH / 256), dim3(256), 0, stream,
                       out, ws, gamma, beta);
}